// Round 7
// baseline (171.117 us; speedup 1.0000x reference)
//
#include <hip/hip_runtime.h>
#include <math.h>

// loss = ALPHA * mean(level_w * (softplus(x) - x*t))
//      + BETA  * sum_{b,e} relu(sig(x[b,dst]) - sig(x[b,src])) / (B*N)
//
// R12: stream-separated K1. Evidence through R11: EVERY structure (fused,
// canonical streaming, deep-batch streaming) pins at ~3 TB/s effective
// while single-read-stream kernels on this chip do 4.9-6.3 TB/s. Theory:
// the per-thread interleaved dual-read (x[i], t[i] same offsets) + write
// mix throttles the memory path. Fix: time-separate the streams --
//  phase A: read x ONLY -> sigmoid->P (store), softplus*w partial, and
//           w*x stashed as fp16 in a 32 KB LDS table;
//  phase B: read t ONLY (columns shifted +256 f4 = 4 KB to decorrelate
//           addresses), multiply vs LDS w*x, accumulate.
// Each phase is copy-like; 1024 staggered blocks keep the device mixed.
// No atomics in K1 (partials -> ws, folded into K2's 256 atomics).
// K2 unchanged (DMA-staged gather pipeline, passed R10/R11).

#define ALPHA_C 1.0f
#define BETA_C  0.5f

constexpr int B = 4096;
constexpr int N = 4096;
constexpr int E = 16384;
constexpr int K1_BLOCKS = B / 4;                 // 1024 tiles of 4 rows
constexpr size_t PG_BYTES = (size_t)B * N * 2;   // 32 MB fp16 P
constexpr size_t WS_NEED = PG_BYTES + K1_BLOCKS * sizeof(float);

typedef _Float16 h4 __attribute__((ext_vector_type(4)));
typedef _Float16 h8 __attribute__((ext_vector_type(8)));

__global__ __launch_bounds__(64) void init_out_kernel(float* out) {
    if (threadIdx.x == 0) out[0] = 0.0f;
}

__device__ __forceinline__ void fast_sig_sp(float x, float& p, float& sp) {
    // q = exp(-|x|) in (0,1]; both sigmoid and softplus from one exp
    float q = __expf(-fabsf(x));
    float d = 1.0f + q;
    float r = __builtin_amdgcn_rcpf(d);     // ~1 ulp approx reciprocal
    p  = (x >= 0.0f) ? r : q * r;           // sigmoid
    sp = fmaxf(x, 0.0f) + __logf(d);        // softplus = max(x,0)+log(1+q)
}

// ---------------- K1: stream-separated sigmoid + BCE ----------------
// 1024 blocks x 512 threads; block = tile (4 rows x full N).
// Phase A (x-stream only): per col, 4 row-loads of x; sigmoid -> P pack
// (tile-major h4-across-rows for K2's DMA); s1 += w*softplus; w*x -> LDS.
// Phase B (t-stream only, +256-col shift): s1 -= (w*x)*t via LDS.
__global__ __launch_bounds__(512, 4) void sig_bce_kernel(
    const float* __restrict__ outputs,
    const float* __restrict__ targets,
    const float* __restrict__ level_w,
    h4*          __restrict__ Pg,
    float*       __restrict__ partials)
{
    __shared__ h4 XL[N];            // 32 KB: XL[4*c + r] = (w.x) row r, col c
    __shared__ float red[8];

    const int tid  = threadIdx.x;
    const int tile = blockIdx.x;                 // 0..1023

    const float4* out4 = (const float4*)outputs;
    const float4* tgt4 = (const float4*)targets;
    const float4* lw4  = (const float4*)level_w;

    float s1 = 0.0f;

    // ---- phase A: x-stream ----
#pragma unroll
    for (int cg = 0; cg < 2; ++cg) {
        const int c = tid + cg * 512;            // f4-column 0..1023
        const float4 w = lw4[c];
        const float wv[4] = {w.x, w.y, w.z, w.w};
        float4 xs[4];
#pragma unroll
        for (int r = 0; r < 4; ++r)
            xs[r] = out4[(size_t)(4 * tile + r) * (N / 4) + c];

        h4 tmp[4];                  // tmp[k][r] = p(row r, node 4c+k)
#pragma unroll
        for (int r = 0; r < 4; ++r) {
            const float xv[4] = {xs[r].x, xs[r].y, xs[r].z, xs[r].w};
            h4 wx;
#pragma unroll
            for (int k = 0; k < 4; ++k) {
                float p, sp;
                fast_sig_sp(xv[k], p, sp);
                s1 = fmaf(wv[k], sp, s1);        // + w*softplus
                tmp[k][r] = (_Float16)p;
                wx[k] = (_Float16)(wv[k] * xv[k]);
            }
            XL[4 * c + r] = wx;                  // fp16 w*x for phase B
        }
        // 32 B contiguous store of 4 h4 slots (tile-major layout for K2 DMA)
        h8 lo = __builtin_shufflevector(tmp[0], tmp[1], 0, 1, 2, 3, 4, 5, 6, 7);
        h8 hi = __builtin_shufflevector(tmp[2], tmp[3], 0, 1, 2, 3, 4, 5, 6, 7);
        h8* dst = (h8*)&Pg[(size_t)tile * N + 4 * c];
        dst[0] = lo;
        dst[1] = hi;
    }
    __syncthreads();

    // ---- phase B: t-stream, columns shifted +256 f4 (4 KB) ----
#pragma unroll
    for (int cg = 0; cg < 2; ++cg) {
        const int c = (tid + 256 + cg * 512) & (N / 4 - 1);
        float4 ts[4];
#pragma unroll
        for (int r = 0; r < 4; ++r)
            ts[r] = tgt4[(size_t)(4 * tile + r) * (N / 4) + c];
#pragma unroll
        for (int r = 0; r < 4; ++r) {
            const h4 wx = XL[4 * c + r];
            const float tv[4] = {ts[r].x, ts[r].y, ts[r].z, ts[r].w};
#pragma unroll
            for (int k = 0; k < 4; ++k)
                s1 = fmaf(-(float)wx[k], tv[k], s1);   // - (w*x)*t
        }
    }

    // block reduce -> plain store (no atomic)
#pragma unroll
    for (int off = 32; off > 0; off >>= 1) s1 += __shfl_down(s1, off, 64);
    const int wave = tid >> 6, lane = tid & 63;
    if (lane == 0) red[wave] = s1;
    __syncthreads();
    if (tid == 0) {
        float a = 0.0f;
#pragma unroll
        for (int v = 0; v < 8; ++v) a += red[v];
        partials[tile] = a;
    }
}

// ---------------- K2: DMA-staged edge gathers + partial fold ----------------
// 256 blocks x 1024 threads; 4 tiles (16 rows) per block; double-buffered
// 32 KB LDS tiles filled by global_load_lds; vmcnt-only barriers.
__global__ __launch_bounds__(1024, 4) void edge_kernel(
    const h4* __restrict__ Pg,
    const int* __restrict__ edge_src,
    const int* __restrict__ edge_dst,
    const float* __restrict__ partials,
    float*     __restrict__ out)
{
    __shared__ h4 Pl[2][N];         // 2 x 32 KB

    const int tid = threadIdx.x;
    const int wv_ = tid >> 6;       // wave 0..15
    const int ln  = tid & 63;
    constexpr int EPT4 = E / 4 / 1024;   // 4 int4-chunks (16 edges)/thread

    const int4* es4 = (const int4*)edge_src;
    const int4* ed4 = (const int4*)edge_dst;

    // DMA one 32 KB tile into Pl[bufi]: per wave 2 x (64 lanes x 16 B) at
    // wave-uniform LDS base (the required global_load_lds dest pattern)
    auto copy_grp = [&](int t, int bufi) {
        const char* gbase = (const char*)&Pg[(size_t)t * N];
#pragma unroll
        for (int c = 0; c < 2; ++c) {
            const int boff = (c * 16 + wv_) * 1024;
            __builtin_amdgcn_global_load_lds(
                (const __attribute__((address_space(1))) void*)(gbase + boff + ln * 16),
                (__attribute__((address_space(3))) void*)((char*)&Pl[bufi][0] + boff),
                16, 0, 0);
        }
    };

    // edge indices into VGPRs (32 regs), issued before the first DMA
    int4 se[EPT4], de[EPT4];
#pragma unroll
    for (int j = 0; j < EPT4; ++j) {
        se[j] = es4[tid + j * 1024];
        de[j] = ed4[tid + j * 1024];
    }
    copy_grp(blockIdx.x * 4 + 0, 0);
    asm volatile("s_waitcnt vmcnt(0)" ::: "memory");   // idx + tile0 landed
    __builtin_amdgcn_s_barrier();

    float s2 = 0.0f;
#pragma unroll
    for (int k = 0; k < 4; ++k) {
        // issue next tile's DMA; it streams under this step's gathers
        if (k + 1 < 4) copy_grp(blockIdx.x * 4 + k + 1, (k + 1) & 1);
        __builtin_amdgcn_sched_barrier(0);

        const h4* Pc = Pl[k & 1];
        h4 acc0 = {0, 0, 0, 0};
        h4 acc1 = {0, 0, 0, 0};
        const h4 zero = {0, 0, 0, 0};
#pragma unroll
        for (int j = 0; j < EPT4; ++j) {
            const int4 s = se[j];
            const int4 d = de[j];
            h4 a0 = Pc[s.x], c0 = Pc[d.x];
            h4 a1 = Pc[s.y], c1 = Pc[d.y];
            h4 a2 = Pc[s.z], c2 = Pc[d.z];
            h4 a3 = Pc[s.w], c3 = Pc[d.w];
            acc0 += __builtin_elementwise_max(c0 - a0, zero);   // v_pk_* fp16
            acc1 += __builtin_elementwise_max(c1 - a1, zero);
            acc0 += __builtin_elementwise_max(c2 - a2, zero);
            acc1 += __builtin_elementwise_max(c3 - a3, zero);
        }
#pragma unroll
        for (int l = 0; l < 4; ++l) s2 += (float)acc0[l] + (float)acc1[l];

        if (k + 1 < 4) {
            // only the in-flight DMA ops remain -> counted sync point;
            // no __syncthreads vmcnt-drain convoy
            asm volatile("s_waitcnt vmcnt(0)" ::: "memory");
            __builtin_amdgcn_s_barrier();
        }
    }

    // block reduce + one atomic (256 total), folding 4 K1 partials
#pragma unroll
    for (int off = 32; off > 0; off >>= 1) s2 += __shfl_down(s2, off, 64);
    __syncthreads();                 // all gathers done before LDS reuse
    float* red = (float*)Pl;
    if (ln == 0) red[wv_] = s2;
    __syncthreads();
    if (tid == 0) {
        float c = 0.0f;
#pragma unroll
        for (int v = 0; v < 16; ++v) c += red[v];
        const float4 pp = ((const float4*)partials)[blockIdx.x];
        const float a = pp.x + pp.y + pp.z + pp.w;
        const float inv = 1.0f / ((float)B * (float)N);
        atomicAdd(out, (ALPHA_C * a + BETA_C * c) * inv);
    }
}

// ---------------- fallback: proven R5 fused kernel ----------------
constexpr int FTHREADS = 512;
constexpr int FR = 4;

__global__ __launch_bounds__(FTHREADS, 8) void hier_loss_fallback(
    const float* __restrict__ outputs,
    const float* __restrict__ targets,
    const float* __restrict__ level_w,
    const int*   __restrict__ edge_src,
    const int*   __restrict__ edge_dst,
    float*       __restrict__ out)
{
    __shared__ h4 P[N];

    const int r0  = blockIdx.x * FR;
    const int tid = threadIdx.x;

    const float4* out4 = (const float4*)outputs;
    const float4* tgt4 = (const float4*)targets;
    const float4* lw4  = (const float4*)level_w;

    float s1 = 0.0f;
#pragma unroll
    for (int j = 0; j < N / 4 / FTHREADS; ++j) {
        const int n4 = tid + j * FTHREADS;
        const float4 w = lw4[n4];
        const float wv[4] = {w.x, w.y, w.z, w.w};
        float4 xs[FR], ts[FR];
#pragma unroll
        for (int r = 0; r < FR; ++r) {
            xs[r] = out4[(size_t)(r0 + r) * (N / 4) + n4];
            ts[r] = tgt4[(size_t)(r0 + r) * (N / 4) + n4];
        }
        h4 tmp[4];
#pragma unroll
        for (int r = 0; r < FR; ++r) {
            const float xv[4] = {xs[r].x, xs[r].y, xs[r].z, xs[r].w};
            const float tv[4] = {ts[r].x, ts[r].y, ts[r].z, ts[r].w};
#pragma unroll
            for (int k = 0; k < 4; ++k) {
                float p, sp;
                fast_sig_sp(xv[k], p, sp);
                s1 = fmaf(wv[k], sp - xv[k] * tv[k], s1);
                tmp[k][r] = (_Float16)p;
            }
        }
#pragma unroll
        for (int k = 0; k < 4; ++k) P[4 * n4 + k] = tmp[k];
    }
    __syncthreads();

    h4 acc0 = {0, 0, 0, 0};
    h4 acc1 = {0, 0, 0, 0};
    const h4 zero = {0, 0, 0, 0};
    const int4* es4 = (const int4*)edge_src;
    const int4* ed4 = (const int4*)edge_dst;
#pragma unroll
    for (int j = 0; j < E / 4 / FTHREADS; ++j) {
        const int i = tid + j * FTHREADS;
        const int4 s = es4[i];
        const int4 d = ed4[i];
        h4 a0 = P[s.x], c0 = P[d.x];
        h4 a1 = P[s.y], c1 = P[d.y];
        h4 a2 = P[s.z], c2 = P[d.z];
        h4 a3 = P[s.w], c3 = P[d.w];
        acc0 += __builtin_elementwise_max(c0 - a0, zero);
        acc1 += __builtin_elementwise_max(c1 - a1, zero);
        acc0 += __builtin_elementwise_max(c2 - a2, zero);
        acc1 += __builtin_elementwise_max(c3 - a3, zero);
    }
    float s2 = 0.0f;
#pragma unroll
    for (int l = 0; l < 4; ++l) s2 += (float)acc0[l] + (float)acc1[l];

#pragma unroll
    for (int off = 32; off > 0; off >>= 1) {
        s1 += __shfl_down(s1, off, 64);
        s2 += __shfl_down(s2, off, 64);
    }
    __syncthreads();
    float* red = (float*)P;
    const int wave = tid >> 6;
    const int lane = tid & 63;
    if (lane == 0) { red[wave] = s1; red[8 + wave] = s2; }
    __syncthreads();
    if (tid == 0) {
        float a = 0.0f, c = 0.0f;
#pragma unroll
        for (int w = 0; w < 8; ++w) { a += red[w]; c += red[8 + w]; }
        const float inv = 1.0f / ((float)B * (float)N);
        atomicAdd(out, (ALPHA_C * a + BETA_C * c) * inv);
    }
}

extern "C" void kernel_launch(void* const* d_in, const int* in_sizes, int n_in,
                              void* d_out, int out_size, void* d_ws, size_t ws_size,
                              hipStream_t stream) {
    const float* outputs = (const float*)d_in[0];
    const float* targets = (const float*)d_in[1];
    const float* level_w = (const float*)d_in[2];
    const int*   edge_src = (const int*)d_in[3];
    const int*   edge_dst = (const int*)d_in[4];
    float* out = (float*)d_out;

    init_out_kernel<<<1, 64, 0, stream>>>(out);
    if (ws_size >= WS_NEED && d_ws != nullptr) {
        h4*    Pg       = (h4*)d_ws;
        float* partials = (float*)((char*)d_ws + PG_BYTES);
        sig_bce_kernel<<<K1_BLOCKS, 512, 0, stream>>>(outputs, targets, level_w,
                                                      Pg, partials);
        edge_kernel<<<256, 1024, 0, stream>>>(Pg, edge_src, edge_dst,
                                              partials, out);
    } else {
        hier_loss_fallback<<<B / FR, FTHREADS, 0, stream>>>(
            outputs, targets, level_w, edge_src, edge_dst, out);
    }
}

// Round 8
// 154.571 us; speedup vs baseline: 1.1070x; 1.1070x over previous
//
#include <hip/hip_runtime.h>
#include <math.h>

// loss = ALPHA * mean(level_w * (softplus(x) - x*t))
//      + BETA  * sum_{b,e} relu(sig(x[b,dst]) - sig(x[b,src])) / (B*N)
//
// R13 = R6 verbatim (best harness-verified: 154.60 us bench, 47.4-50.8 us
// dispatches). Session conclusion: this op pins at ~2.7-3.3 TB/s effective
// across 7 structures (fused, pinned-pipeline, wave-specialized, 2-kernel
// split, stream-separated); the rate is invariant to data residency
// (L3-warm pass = same duration), so it is not HBM/atomics/LDS/VALU/
// occupancy bound -- a structural per-CU memory-path limit for this
// access mix. Fused is optimal because it moves the minimal 128 MB
// (the split pays +64 MB P round-trip = +20 us at the structural rate).
// Floor ~= 128 MB / 3.3 TB/s ~= 43 us; measured 47 us is within ~10%.

#define ALPHA_C 1.0f
#define BETA_C  0.5f

constexpr int B = 4096;
constexpr int N = 4096;
constexpr int E = 16384;
constexpr int THREADS = 1024;
constexpr int R = 4;            // rows per group
constexpr int GRID = 256;       // 1 block/CU
constexpr int GPB = (B / R) / GRID;     // 4 groups per block
constexpr int EJ = E / 4 / THREADS;     // 4 edge-iters per thread

typedef _Float16 h4 __attribute__((ext_vector_type(4)));

__global__ __launch_bounds__(64) void init_out_kernel(float* out) {
    if (threadIdx.x == 0) out[0] = 0.0f;
}

__device__ __forceinline__ void fast_sig_sp(float x, float& p, float& sp) {
    // q = exp(-|x|) in (0,1]; both sigmoid and softplus from one exp
    float q = __expf(-fabsf(x));
    float d = 1.0f + q;
    float r = __builtin_amdgcn_rcpf(d);     // ~1 ulp approx reciprocal
    p  = (x >= 0.0f) ? r : q * r;           // sigmoid
    sp = fmaxf(x, 0.0f) + __logf(d);        // softplus = max(x,0)+log(1+q)
}

__global__ __launch_bounds__(THREADS, 4) void hier_loss_kernel(
    const float* __restrict__ outputs,
    const float* __restrict__ targets,
    const float* __restrict__ level_w,
    const int*   __restrict__ edge_src,
    const int*   __restrict__ edge_dst,
    float*       __restrict__ out)
{
    __shared__ h4 P[2][N];          // 64 KB, double-buffered fp16 sigmoid rows

    const int tid = threadIdx.x;
    const int g0  = blockIdx.x * GPB;   // first row-group of this block

    const float4* out4 = (const float4*)outputs;
    const float4* tgt4 = (const float4*)targets;
    const float4* lw4  = (const float4*)level_w;
    const int4*   es4  = (const int4*)edge_src;
    const int4*   ed4  = (const int4*)edge_dst;

    // level weights: this thread's float4-column, constant across groups
    const float4 w = lw4[tid];
    const float wv[4] = {w.x, w.y, w.z, w.w};

    // edge indices: load once, reuse for all GPB groups (32 VGPRs)
    int4 se[EJ], de[EJ];
#pragma unroll
    for (int j = 0; j < EJ; ++j) {
        se[j] = es4[tid + j * THREADS];
        de[j] = ed4[tid + j * THREADS];
    }

    float s1 = 0.0f, s2 = 0.0f;
    float4 xs[R], ts[R];

    // ---- prologue: load + transform group g0 into P[0] ----
#pragma unroll
    for (int r = 0; r < R; ++r) {
        const size_t row = (size_t)((g0 + 0) * R + r) * (N / 4) + tid;
        xs[r] = out4[row];
        ts[r] = tgt4[row];
    }
    {
        h4 tmp[4];
#pragma unroll
        for (int r = 0; r < R; ++r) {
            const float xv[4] = {xs[r].x, xs[r].y, xs[r].z, xs[r].w};
            const float tv[4] = {ts[r].x, ts[r].y, ts[r].z, ts[r].w};
#pragma unroll
            for (int k = 0; k < 4; ++k) {
                float p, sp;
                fast_sig_sp(xv[k], p, sp);
                s1 = fmaf(wv[k], sp - xv[k] * tv[k], s1);
                tmp[k][r] = (_Float16)p;
            }
        }
#pragma unroll
        for (int k = 0; k < 4; ++k) P[0][4 * tid + k] = tmp[k];
    }
    __syncthreads();

    // ---- pipelined main loop: edges(g) overlap loads(g+1) ----
#pragma unroll
    for (int kg = 0; kg < GPB; ++kg) {
        // issue next group's global loads early; latency hidden by edge phase
        if (kg + 1 < GPB) {
#pragma unroll
            for (int r = 0; r < R; ++r) {
                const size_t row = (size_t)((g0 + kg + 1) * R + r) * (N / 4) + tid;
                xs[r] = out4[row];
                ts[r] = tgt4[row];
            }
        }

        // edge consistency on current buffer; one b64 gather covers 4 rows
        const h4* Pc = P[kg & 1];
        h4 acc0 = {0, 0, 0, 0};
        h4 acc1 = {0, 0, 0, 0};
        const h4 zero = {0, 0, 0, 0};
#pragma unroll
        for (int j = 0; j < EJ; ++j) {
            const int4 s = se[j];
            const int4 d = de[j];
            h4 a0 = Pc[s.x], c0 = Pc[d.x];
            h4 a1 = Pc[s.y], c1 = Pc[d.y];
            h4 a2 = Pc[s.z], c2 = Pc[d.z];
            h4 a3 = Pc[s.w], c3 = Pc[d.w];
            acc0 += __builtin_elementwise_max(c0 - a0, zero);   // v_pk_* fp16
            acc1 += __builtin_elementwise_max(c1 - a1, zero);
            acc0 += __builtin_elementwise_max(c2 - a2, zero);
            acc1 += __builtin_elementwise_max(c3 - a3, zero);
        }
#pragma unroll
        for (int l = 0; l < 4; ++l) s2 += (float)acc0[l] + (float)acc1[l];

        // transform next group's landed registers into the other buffer
        if (kg + 1 < GPB) {
            h4 tmp[4];
#pragma unroll
            for (int r = 0; r < R; ++r) {
                const float xv[4] = {xs[r].x, xs[r].y, xs[r].z, xs[r].w};
                const float tv[4] = {ts[r].x, ts[r].y, ts[r].z, ts[r].w};
#pragma unroll
                for (int k = 0; k < 4; ++k) {
                    float p, sp;
                    fast_sig_sp(xv[k], p, sp);
                    s1 = fmaf(wv[k], sp - xv[k] * tv[k], s1);
                    tmp[k][r] = (_Float16)p;
                }
            }
#pragma unroll
            for (int k = 0; k < 4; ++k) P[(kg + 1) & 1][4 * tid + k] = tmp[k];
        }
        __syncthreads();   // P[kg&1] reads done; P[(kg+1)&1] writes visible
    }

    // ---- block reduce: wave64 shuffle, cross-wave via reused LDS ----
#pragma unroll
    for (int off = 32; off > 0; off >>= 1) {
        s1 += __shfl_down(s1, off, 64);
        s2 += __shfl_down(s2, off, 64);
    }
    float* red = (float*)P;              // safe after final loop barrier
    const int wave = tid >> 6;           // 16 waves
    const int lane = tid & 63;
    if (lane == 0) { red[wave] = s1; red[16 + wave] = s2; }
    __syncthreads();
    if (tid == 0) {
        float a = 0.0f, c = 0.0f;
#pragma unroll
        for (int v = 0; v < 16; ++v) { a += red[v]; c += red[16 + v]; }
        const float inv = 1.0f / ((float)B * (float)N);
        atomicAdd(out, (ALPHA_C * a + BETA_C * c) * inv);
    }
}

extern "C" void kernel_launch(void* const* d_in, const int* in_sizes, int n_in,
                              void* d_out, int out_size, void* d_ws, size_t ws_size,
                              hipStream_t stream) {
    const float* outputs = (const float*)d_in[0];
    const float* targets = (const float*)d_in[1];
    const float* level_w = (const float*)d_in[2];
    const int*   edge_src = (const int*)d_in[3];
    const int*   edge_dst = (const int*)d_in[4];
    float* out = (float*)d_out;

    init_out_kernel<<<1, 64, 0, stream>>>(out);
    hier_loss_kernel<<<GRID, THREADS, 0, stream>>>(outputs, targets, level_w,
                                                   edge_src, edge_dst, out);
}